// Round 1
// baseline (1126.876 us; speedup 1.0000x reference)
//
#include <hip/hip_runtime.h>
#include <hip/hip_bf16.h>

#define N_TOK 1024
#define DIM   1024
#define FFN   2048
#define NE    32
#define TOPK  4

// ---------------- router: logits, probs, top-4 ----------------
__global__ void router_kernel(const float* __restrict__ x, const float* __restrict__ gw,
                              const float* __restrict__ gb, float* __restrict__ probs_mat,
                              int* __restrict__ top_idx, float* __restrict__ top_w) {
    __shared__ float part[8][32];
    __shared__ float logit_s[32];
    int t = threadIdx.x;
    int token = blockIdx.x;
    int e = t & 31, p = t >> 5;
    const float* xr = x + (size_t)token * DIM;
    float acc = 0.f;
    int i0 = p * (DIM / 8);
    for (int i = 0; i < DIM / 8; ++i)
        acc += xr[i0 + i] * gw[(size_t)(i0 + i) * NE + e];
    part[p][e] = acc;
    __syncthreads();
    if (t < 32) {
        float l = gb[t];
        for (int q = 0; q < 8; ++q) l += part[q][t];
        logit_s[t] = l;
    }
    __syncthreads();
    if (t == 0) {
        float l[32];
        for (int i = 0; i < 32; ++i) l[i] = logit_s[i];
        // full softmax probs for aux loss
        float m = -1e30f;
        for (int i = 0; i < 32; ++i) m = fmaxf(m, l[i]);
        float denom = 0.f;
        for (int i = 0; i < 32; ++i) denom += expf(l[i] - m);
        for (int i = 0; i < 32; ++i)
            probs_mat[(size_t)token * 32 + i] = expf(l[i] - m) / denom;
        // top-4
        float lc[32];
        for (int i = 0; i < 32; ++i) lc[i] = l[i];
        int idx[TOPK]; float val[TOPK];
        for (int k = 0; k < TOPK; ++k) {
            int bj = 0; float bv = lc[0];
            for (int i = 1; i < 32; ++i) if (lc[i] > bv) { bv = lc[i]; bj = i; }
            idx[k] = bj; val[k] = bv; lc[bj] = -1e30f;
        }
        float mm = val[0];
        float w[TOPK]; float ss = 0.f;
        for (int k = 0; k < TOPK; ++k) { w[k] = expf(val[k] - mm); ss += w[k]; }
        for (int k = 0; k < TOPK; ++k) {
            top_idx[token * TOPK + k] = idx[k];
            top_w[token * TOPK + k] = w[k] / ss;
        }
    }
}

// ---------------- aux loss + counts + offsets (1 block) ----------------
__global__ void aux_kernel(const float* __restrict__ probs_mat, const int* __restrict__ top_idx,
                           const float* __restrict__ load_ema, int* __restrict__ counts,
                           int* __restrict__ offsets, int* __restrict__ cursors,
                           float* __restrict__ out_aux) {
    __shared__ int cnt_s[32];
    __shared__ float ps[32];
    __shared__ float psum_part[8][32];
    int t = threadIdx.x;
    if (t < 32) cnt_s[t] = 0;
    __syncthreads();
    for (int i = t; i < N_TOK * TOPK; i += 256) atomicAdd(&cnt_s[top_idx[i]], 1);
    int e = t & 31, p = t >> 5;
    float s = 0.f;
    for (int tok = p; tok < N_TOK; tok += 8) s += probs_mat[(size_t)tok * 32 + e];
    psum_part[p][e] = s;
    __syncthreads();
    if (t < 32) {
        float tot = 0.f;
        for (int q = 0; q < 8; ++q) tot += psum_part[q][t];
        ps[t] = tot;
        counts[t] = cnt_s[t];
    }
    __syncthreads();
    if (t == 0) {
        int off = 0;
        for (int i = 0; i < 32; ++i) { offsets[i] = off; cursors[i] = off; off += cnt_s[i]; }
        offsets[32] = off;
        float base = 0.f;
        for (int i = 0; i < 32; ++i) {
            float frac = (float)cnt_s[i] / (float)(N_TOK * TOPK);
            float mp = ps[i] / (float)N_TOK;
            base += frac * mp;
        }
        base *= (float)NE;
        float sum_ema = 0.f;
        for (int i = 0; i < 32; ++i) sum_ema += load_ema[i];
        float H = 0.f;
        for (int i = 0; i < 32; ++i) {
            float lp = load_ema[i] / (sum_ema + 1e-8f);
            H -= lp * logf(lp + 1e-8f);
        }
        float reg = logf((float)NE) - H;
        *out_aux = base + 0.001f * reg;
    }
}

// ---------------- scatter token-expert pairs ----------------
__global__ void scatter_kernel(const int* __restrict__ top_idx, int* __restrict__ cursors,
                               int* __restrict__ pair_token, int* __restrict__ pair_of) {
    int token = blockIdx.x * 256 + threadIdx.x;
    if (token >= N_TOK) return;
    for (int s = 0; s < TOPK; ++s) {
        int e = top_idx[token * TOPK + s];
        int pos = atomicAdd(&cursors[e], 1);
        pair_token[pos] = token;
        pair_of[token * TOPK + s] = pos;
    }
}

// ---------------- GEMM1: h = GELU(Xg @ W1[e] + b1[e]) ----------------
__global__ __launch_bounds__(256) void gemm1_kernel(const float* __restrict__ x,
        const float* __restrict__ w1, const float* __restrict__ b1,
        const int* __restrict__ offsets, const int* __restrict__ pair_token,
        float* __restrict__ h) {
    int e = blockIdx.z;
    int m0 = offsets[e], m1 = offsets[e + 1];
    int Me = m1 - m0;
    int rowBase = blockIdx.y * 64;
    if (rowBase >= Me) return;
    int f0 = blockIdx.x * 64;
    __shared__ float As[16][64];
    __shared__ float Bs[16][64];
    __shared__ int toks[64];
    int t = threadIdx.x;
    if (t < 64) {
        int r = rowBase + t;
        if (r >= Me) r = Me - 1;
        toks[t] = pair_token[m0 + r];
    }
    int tm = (t >> 4) * 4;
    int tn = (t & 15) * 4;
    float c[4][4] = {};
    int lr = t >> 2;
    int lkq = (t & 3) * 4;
    int bk_row = t >> 4;
    int bf4 = (t & 15) * 4;
    __syncthreads();
    for (int k0 = 0; k0 < DIM; k0 += 16) {
        float4 av = *(const float4*)&x[(size_t)toks[lr] * DIM + k0 + lkq];
        float4 bv = *(const float4*)&w1[((size_t)e * DIM + k0 + bk_row) * FFN + f0 + bf4];
        __syncthreads();
        As[lkq + 0][lr] = av.x; As[lkq + 1][lr] = av.y;
        As[lkq + 2][lr] = av.z; As[lkq + 3][lr] = av.w;
        *(float4*)&Bs[bk_row][bf4] = bv;
        __syncthreads();
#pragma unroll
        for (int k = 0; k < 16; ++k) {
            float a0 = As[k][tm], a1 = As[k][tm + 1], a2 = As[k][tm + 2], a3 = As[k][tm + 3];
            float b0 = Bs[k][tn], b1_ = Bs[k][tn + 1], b2_ = Bs[k][tn + 2], b3_ = Bs[k][tn + 3];
            c[0][0] += a0 * b0; c[0][1] += a0 * b1_; c[0][2] += a0 * b2_; c[0][3] += a0 * b3_;
            c[1][0] += a1 * b0; c[1][1] += a1 * b1_; c[1][2] += a1 * b2_; c[1][3] += a1 * b3_;
            c[2][0] += a2 * b0; c[2][1] += a2 * b1_; c[2][2] += a2 * b2_; c[2][3] += a2 * b3_;
            c[3][0] += a3 * b0; c[3][1] += a3 * b1_; c[3][2] += a3 * b2_; c[3][3] += a3 * b3_;
        }
    }
#pragma unroll
    for (int i = 0; i < 4; ++i) {
        int r = rowBase + tm + i;
        if (r >= Me) continue;
        size_t p = (size_t)(m0 + r);
        float4 o;
        float* oo = &o.x;
#pragma unroll
        for (int j = 0; j < 4; ++j) {
            float v = c[i][j] + b1[(size_t)e * FFN + f0 + tn + j];
            oo[j] = 0.5f * v * (1.f + erff(v * 0.70710678118654752f));
        }
        *(float4*)&h[p * FFN + f0 + tn] = o;
    }
}

// ---------------- GEMM2: y = h @ W2[e] ----------------
__global__ __launch_bounds__(256) void gemm2_kernel(const float* __restrict__ h,
        const float* __restrict__ w2, const int* __restrict__ offsets,
        float* __restrict__ y) {
    int e = blockIdx.z;
    int m0 = offsets[e], m1 = offsets[e + 1];
    int Me = m1 - m0;
    int rowBase = blockIdx.y * 64;
    if (rowBase >= Me) return;
    int d0 = blockIdx.x * 64;
    __shared__ float As[16][64];
    __shared__ float Bs[16][64];
    int t = threadIdx.x;
    int tm = (t >> 4) * 4;
    int tn = (t & 15) * 4;
    float c[4][4] = {};
    int lr = t >> 2;
    int lkq = (t & 3) * 4;
    int bk_row = t >> 4;
    int bf4 = (t & 15) * 4;
    int arow = rowBase + lr;
    if (arow >= Me) arow = Me - 1;
    size_t ap = (size_t)(m0 + arow);
    for (int k0 = 0; k0 < FFN; k0 += 16) {
        float4 av = *(const float4*)&h[ap * FFN + k0 + lkq];
        float4 bv = *(const float4*)&w2[((size_t)e * FFN + k0 + bk_row) * DIM + d0 + bf4];
        __syncthreads();
        As[lkq + 0][lr] = av.x; As[lkq + 1][lr] = av.y;
        As[lkq + 2][lr] = av.z; As[lkq + 3][lr] = av.w;
        *(float4*)&Bs[bk_row][bf4] = bv;
        __syncthreads();
#pragma unroll
        for (int k = 0; k < 16; ++k) {
            float a0 = As[k][tm], a1 = As[k][tm + 1], a2 = As[k][tm + 2], a3 = As[k][tm + 3];
            float b0 = Bs[k][tn], b1_ = Bs[k][tn + 1], b2_ = Bs[k][tn + 2], b3_ = Bs[k][tn + 3];
            c[0][0] += a0 * b0; c[0][1] += a0 * b1_; c[0][2] += a0 * b2_; c[0][3] += a0 * b3_;
            c[1][0] += a1 * b0; c[1][1] += a1 * b1_; c[1][2] += a1 * b2_; c[1][3] += a1 * b3_;
            c[2][0] += a2 * b0; c[2][1] += a2 * b1_; c[2][2] += a2 * b2_; c[2][3] += a2 * b3_;
            c[3][0] += a3 * b0; c[3][1] += a3 * b1_; c[3][2] += a3 * b2_; c[3][3] += a3 * b3_;
        }
    }
#pragma unroll
    for (int i = 0; i < 4; ++i) {
        int r = rowBase + tm + i;
        if (r >= Me) continue;
        size_t p = (size_t)(m0 + r);
        float4 o = make_float4(c[i][0], c[i][1], c[i][2], c[i][3]);
        *(float4*)&y[p * DIM + d0 + tn] = o;
    }
}

// ---------------- combine: out = sum_s w_s * (y + b2[e_s]) ----------------
__global__ void combine_kernel(const float* __restrict__ y, const float* __restrict__ b2,
        const int* __restrict__ top_idx, const float* __restrict__ top_w,
        const int* __restrict__ pair_of, float* __restrict__ out) {
    int token = blockIdx.y;
    int j = blockIdx.x * 256 + threadIdx.x;
    float acc = 0.f;
#pragma unroll
    for (int s = 0; s < TOPK; ++s) {
        int e = top_idx[token * TOPK + s];
        float w = top_w[token * TOPK + s];
        int p = pair_of[token * TOPK + s];
        acc += w * (y[(size_t)p * DIM + j] + b2[(size_t)e * DIM + j]);
    }
    out[(size_t)token * DIM + j] = acc;
}

extern "C" void kernel_launch(void* const* d_in, const int* in_sizes, int n_in,
                              void* d_out, int out_size, void* d_ws, size_t ws_size,
                              hipStream_t stream) {
    const float* x       = (const float*)d_in[0];
    const float* gate_w  = (const float*)d_in[1];
    const float* gate_b  = (const float*)d_in[2];
    const float* w1      = (const float*)d_in[3];
    const float* b1      = (const float*)d_in[4];
    const float* w2      = (const float*)d_in[5];
    const float* b2      = (const float*)d_in[6];
    const float* load_ema= (const float*)d_in[7];
    float* out = (float*)d_out;

    // workspace layout (element offsets, all 16B-aligned)
    char* base = (char*)d_ws;
    size_t off = 0;
    auto alloc = [&](size_t bytes) {
        void* p = base + off;
        off = (off + bytes + 15) & ~(size_t)15;
        return p;
    };
    float* probs_mat = (float*)alloc(N_TOK * 32 * sizeof(float));
    int*   top_idx   = (int*)  alloc(N_TOK * TOPK * sizeof(int));
    float* top_w     = (float*)alloc(N_TOK * TOPK * sizeof(float));
    int*   counts    = (int*)  alloc(32 * sizeof(int));
    int*   offsets   = (int*)  alloc(33 * sizeof(int));
    int*   cursors   = (int*)  alloc(32 * sizeof(int));
    int*   pair_token= (int*)  alloc(N_TOK * TOPK * sizeof(int));
    int*   pair_of   = (int*)  alloc(N_TOK * TOPK * sizeof(int));
    float* h         = (float*)alloc((size_t)N_TOK * TOPK * FFN * sizeof(float));
    float* y         = (float*)alloc((size_t)N_TOK * TOPK * DIM * sizeof(float));

    router_kernel<<<N_TOK, 256, 0, stream>>>(x, gate_w, gate_b, probs_mat, top_idx, top_w);
    aux_kernel<<<1, 256, 0, stream>>>(probs_mat, top_idx, load_ema, counts, offsets, cursors,
                                      out + (size_t)N_TOK * DIM);
    scatter_kernel<<<(N_TOK + 255) / 256, 256, 0, stream>>>(top_idx, cursors, pair_token, pair_of);
    {
        dim3 grid(FFN / 64, 16, NE);
        gemm1_kernel<<<grid, 256, 0, stream>>>(x, w1, b1, offsets, pair_token, h);
    }
    {
        dim3 grid(DIM / 64, 16, NE);
        gemm2_kernel<<<grid, 256, 0, stream>>>(h, w2, offsets, y);
    }
    {
        dim3 grid(DIM / 256, N_TOK);
        combine_kernel<<<grid, 256, 0, stream>>>(y, b2, top_idx, top_w, pair_of, out);
    }
}

// Round 2
// 759.336 us; speedup vs baseline: 1.4840x; 1.4840x over previous
//
#include <hip/hip_runtime.h>
#include <hip/hip_bf16.h>
#include <cmath>

#define N_TOK 1024
#define DIM   1024
#define FFN   2048
#define NE    32
#define TOPK  4
#define TM    256
#define TN    64
#define BK    32
#define BS_STRIDE 40   // bf16 elems per Bs row (80 B) — bank-spread, 16B-aligned

typedef __attribute__((ext_vector_type(8))) short bf16x8;
typedef __attribute__((ext_vector_type(4))) float f32x4;

#define GLOBAL_AS __attribute__((address_space(1)))
#define LDS_AS    __attribute__((address_space(3)))

__device__ __forceinline__ void g2lds16(const void* g, void* l) {
    __builtin_amdgcn_global_load_lds((const GLOBAL_AS void*)g, (LDS_AS void*)l, 16, 0, 0);
}

// ---------------- router: logits, probs, top-4 (fp32, exact routing) ----------------
__global__ void router_kernel(const float* __restrict__ x, const float* __restrict__ gw,
                              const float* __restrict__ gb, float* __restrict__ probs_mat,
                              int* __restrict__ top_idx, float* __restrict__ top_w) {
    __shared__ float part[8][32];
    __shared__ float logit_s[32];
    int t = threadIdx.x;
    int token = blockIdx.x;
    int e = t & 31, p = t >> 5;
    const float* xr = x + (size_t)token * DIM;
    float acc = 0.f;
    int i0 = p * (DIM / 8);
    for (int i = 0; i < DIM / 8; ++i)
        acc += xr[i0 + i] * gw[(size_t)(i0 + i) * NE + e];
    part[p][e] = acc;
    __syncthreads();
    if (t < 32) {
        float l = gb[t];
        for (int q = 0; q < 8; ++q) l += part[q][t];
        logit_s[t] = l;
    }
    __syncthreads();
    if (t == 0) {
        float l[32];
        for (int i = 0; i < 32; ++i) l[i] = logit_s[i];
        float m = -1e30f;
        for (int i = 0; i < 32; ++i) m = fmaxf(m, l[i]);
        float denom = 0.f;
        for (int i = 0; i < 32; ++i) denom += expf(l[i] - m);
        for (int i = 0; i < 32; ++i)
            probs_mat[(size_t)token * 32 + i] = expf(l[i] - m) / denom;
        float lc[32];
        for (int i = 0; i < 32; ++i) lc[i] = l[i];
        int idx[TOPK]; float val[TOPK];
        for (int k = 0; k < TOPK; ++k) {
            int bj = 0; float bv = lc[0];
            for (int i = 1; i < 32; ++i) if (lc[i] > bv) { bv = lc[i]; bj = i; }
            idx[k] = bj; val[k] = bv; lc[bj] = -1e30f;
        }
        float mm = val[0];
        float w[TOPK]; float ss = 0.f;
        for (int k = 0; k < TOPK; ++k) { w[k] = expf(val[k] - mm); ss += w[k]; }
        for (int k = 0; k < TOPK; ++k) {
            top_idx[token * TOPK + k] = idx[k];
            top_w[token * TOPK + k] = w[k] / ss;
        }
    }
}

// ---------------- aux loss + counts + offsets (1 block) ----------------
__global__ void aux_kernel(const float* __restrict__ probs_mat, const int* __restrict__ top_idx,
                           const float* __restrict__ load_ema, int* __restrict__ counts,
                           int* __restrict__ offsets, int* __restrict__ cursors,
                           float* __restrict__ out_aux) {
    __shared__ int cnt_s[32];
    __shared__ float ps[32];
    __shared__ float psum_part[8][32];
    int t = threadIdx.x;
    if (t < 32) cnt_s[t] = 0;
    __syncthreads();
    for (int i = t; i < N_TOK * TOPK; i += 256) atomicAdd(&cnt_s[top_idx[i]], 1);
    int e = t & 31, p = t >> 5;
    float s = 0.f;
    for (int tok = p; tok < N_TOK; tok += 8) s += probs_mat[(size_t)tok * 32 + e];
    psum_part[p][e] = s;
    __syncthreads();
    if (t < 32) {
        float tot = 0.f;
        for (int q = 0; q < 8; ++q) tot += psum_part[q][t];
        ps[t] = tot;
        counts[t] = cnt_s[t];
    }
    __syncthreads();
    if (t == 0) {
        int off = 0;
        for (int i = 0; i < 32; ++i) { offsets[i] = off; cursors[i] = off; off += cnt_s[i]; }
        offsets[32] = off;
        float base = 0.f;
        for (int i = 0; i < 32; ++i) {
            float frac = (float)cnt_s[i] / (float)(N_TOK * TOPK);
            float mp = ps[i] / (float)N_TOK;
            base += frac * mp;
        }
        base *= (float)NE;
        float sum_ema = 0.f;
        for (int i = 0; i < 32; ++i) sum_ema += load_ema[i];
        float H = 0.f;
        for (int i = 0; i < 32; ++i) {
            float lp = load_ema[i] / (sum_ema + 1e-8f);
            H -= lp * logf(lp + 1e-8f);
        }
        float reg = logf((float)NE) - H;
        *out_aux = base + 0.001f * reg;
    }
}

// ---------------- scatter token-expert pairs ----------------
__global__ void scatter_kernel(const int* __restrict__ top_idx, int* __restrict__ cursors,
                               int* __restrict__ pair_token, int* __restrict__ pair_of) {
    int token = blockIdx.x * 256 + threadIdx.x;
    if (token >= N_TOK) return;
    for (int s = 0; s < TOPK; ++s) {
        int e = top_idx[token * TOPK + s];
        int pos = atomicAdd(&cursors[e], 1);
        pair_token[pos] = token;
        pair_of[token * TOPK + s] = pos;
    }
}

// ---------------- x -> bf16 ----------------
__global__ void convert_x_kernel(const float* __restrict__ x, __hip_bfloat16* __restrict__ xb) {
    int i = (blockIdx.x * 256 + threadIdx.x) * 4;
    float4 v = *(const float4*)&x[i];
    union { __hip_bfloat16 h[4]; ushort4 u; } pk;
    pk.h[0] = __float2bfloat16(v.x);
    pk.h[1] = __float2bfloat16(v.y);
    pk.h[2] = __float2bfloat16(v.z);
    pk.h[3] = __float2bfloat16(v.w);
    *(ushort4*)&xb[i] = pk.u;
}

// ---------------- GEMM1: h = bf16(GELU(gather(xb) @ bf16(W1[e]) + b1[e])) ----------------
__global__ __launch_bounds__(256) void gemm1_kernel(
        const __hip_bfloat16* __restrict__ xb, const float* __restrict__ w1,
        const float* __restrict__ b1, const int* __restrict__ offsets,
        const int* __restrict__ pair_token, __hip_bfloat16* __restrict__ h) {
    int e = blockIdx.z;
    int m0 = offsets[e], Me = offsets[e + 1] - m0;
    int rowBase = blockIdx.y * TM;
    if (rowBase >= Me) return;
    int mlim = Me - rowBase; if (mlim > TM) mlim = TM;
    int f0 = blockIdx.x * TN;

    __shared__ __hip_bfloat16 As[TM * BK];        // [m][k] row-major, 64B rows
    __shared__ __hip_bfloat16 Bs[TN * BS_STRIDE]; // [n][k], 80B row stride
    __shared__ int toks[TM];

    int t = threadIdx.x;
    int w = t >> 6, ln = t & 63;
    int q = ln >> 4, lj = ln & 15;
    { int r = t < mlim ? t : mlim - 1; toks[t] = pair_token[m0 + rowBase + r]; }
    bool act = (w * 64) < mlim;

    int a_sub = ln >> 2, a_part = ln & 3;
    int bn = ln, bkb = w * 8;

    f32x4 acc[4][4] = {};

    for (int k0 = 0; k0 < DIM; k0 += BK) {
        __syncthreads();
        if (act) {
#pragma unroll
            for (int i = 0; i < 4; ++i) {
                int rit = w * 64 + i * 16 + a_sub;
                const __hip_bfloat16* src = xb + (size_t)toks[rit] * DIM + k0 + a_part * 8;
                g2lds16(src, As + (w * 64 + i * 16) * BK);
            }
        }
        // B: fp32 -> bf16 -> LDS (transposed [n][k])
        {
            const float* bp = w1 + ((size_t)e * DIM + k0 + bkb) * FFN + f0 + bn;
            float bv[8];
#pragma unroll
            for (int j = 0; j < 8; ++j) bv[j] = bp[(size_t)j * FFN];
            union { __hip_bfloat16 hb[8]; int4 v; } u;
#pragma unroll
            for (int j = 0; j < 8; ++j) u.hb[j] = __float2bfloat16(bv[j]);
            *(int4*)&Bs[bn * BS_STRIDE + bkb] = u.v;
        }
        __syncthreads();
        if (act) {
            bf16x8 af[4], bf[4];
#pragma unroll
            for (int ms = 0; ms < 4; ++ms)
                af[ms] = *(const bf16x8*)&As[(w * 64 + ms * 16 + lj) * BK + q * 8];
#pragma unroll
            for (int ns = 0; ns < 4; ++ns)
                bf[ns] = *(const bf16x8*)&Bs[(ns * 16 + lj) * BS_STRIDE + q * 8];
#pragma unroll
            for (int ms = 0; ms < 4; ++ms)
#pragma unroll
                for (int ns = 0; ns < 4; ++ns)
                    acc[ms][ns] = __builtin_amdgcn_mfma_f32_16x16x32_bf16(af[ms], bf[ns], acc[ms][ns], 0, 0, 0);
        }
    }
    if (!act) return;
#pragma unroll
    for (int ms = 0; ms < 4; ++ms) {
#pragma unroll
        for (int rr = 0; rr < 4; ++rr) {
            int rit = w * 64 + ms * 16 + q * 4 + rr;
            if (rit >= mlim) continue;
            size_t rowG = (size_t)(m0 + rowBase + rit);
#pragma unroll
            for (int ns = 0; ns < 4; ++ns) {
                int col = f0 + ns * 16 + lj;
                float v = acc[ms][ns][rr] + b1[(size_t)e * FFN + col];
                float g = 0.5f * v * (1.f + erff(v * 0.70710678118654752f));
                h[rowG * FFN + col] = __float2bfloat16(g);
            }
        }
    }
}

// ---------------- GEMM2: y = h @ bf16(W2[e])  (fp32 out, bias in combine) ----------------
__global__ __launch_bounds__(256) void gemm2_kernel(
        const __hip_bfloat16* __restrict__ h, const float* __restrict__ w2,
        const int* __restrict__ offsets, float* __restrict__ y) {
    int e = blockIdx.z;
    int m0 = offsets[e], Me = offsets[e + 1] - m0;
    int rowBase = blockIdx.y * TM;
    if (rowBase >= Me) return;
    int mlim = Me - rowBase; if (mlim > TM) mlim = TM;
    int d0 = blockIdx.x * TN;

    __shared__ __hip_bfloat16 As[TM * BK];
    __shared__ __hip_bfloat16 Bs[TN * BS_STRIDE];

    int t = threadIdx.x;
    int w = t >> 6, ln = t & 63;
    int q = ln >> 4, lj = ln & 15;
    bool act = (w * 64) < mlim;

    int a_sub = ln >> 2, a_part = ln & 3;
    int bn = ln, bkb = w * 8;

    f32x4 acc[4][4] = {};

    for (int k0 = 0; k0 < FFN; k0 += BK) {
        __syncthreads();
        if (act) {
#pragma unroll
            for (int i = 0; i < 4; ++i) {
                int rit = w * 64 + i * 16 + a_sub;
                if (rit >= mlim) rit = mlim - 1;
                const __hip_bfloat16* src = h + (size_t)(m0 + rowBase + rit) * FFN + k0 + a_part * 8;
                g2lds16(src, As + (w * 64 + i * 16) * BK);
            }
        }
        {
            const float* bp = w2 + ((size_t)e * FFN + k0 + bkb) * DIM + d0 + bn;
            float bv[8];
#pragma unroll
            for (int j = 0; j < 8; ++j) bv[j] = bp[(size_t)j * DIM];
            union { __hip_bfloat16 hb[8]; int4 v; } u;
#pragma unroll
            for (int j = 0; j < 8; ++j) u.hb[j] = __float2bfloat16(bv[j]);
            *(int4*)&Bs[bn * BS_STRIDE + bkb] = u.v;
        }
        __syncthreads();
        if (act) {
            bf16x8 af[4], bf[4];
#pragma unroll
            for (int ms = 0; ms < 4; ++ms)
                af[ms] = *(const bf16x8*)&As[(w * 64 + ms * 16 + lj) * BK + q * 8];
#pragma unroll
            for (int ns = 0; ns < 4; ++ns)
                bf[ns] = *(const bf16x8*)&Bs[(ns * 16 + lj) * BS_STRIDE + q * 8];
#pragma unroll
            for (int ms = 0; ms < 4; ++ms)
#pragma unroll
                for (int ns = 0; ns < 4; ++ns)
                    acc[ms][ns] = __builtin_amdgcn_mfma_f32_16x16x32_bf16(af[ms], bf[ns], acc[ms][ns], 0, 0, 0);
        }
    }
    if (!act) return;
#pragma unroll
    for (int ms = 0; ms < 4; ++ms) {
#pragma unroll
        for (int rr = 0; rr < 4; ++rr) {
            int rit = w * 64 + ms * 16 + q * 4 + rr;
            if (rit >= mlim) continue;
            size_t rowG = (size_t)(m0 + rowBase + rit);
#pragma unroll
            for (int ns = 0; ns < 4; ++ns)
                y[rowG * DIM + d0 + ns * 16 + lj] = acc[ms][ns][rr];
        }
    }
}

// ---------------- combine: out = sum_s w_s * (y + b2[e_s]) ----------------
__global__ void combine_kernel(const float* __restrict__ y, const float* __restrict__ b2,
        const int* __restrict__ top_idx, const float* __restrict__ top_w,
        const int* __restrict__ pair_of, float* __restrict__ out) {
    int token = blockIdx.y;
    int j = blockIdx.x * 256 + threadIdx.x;
    float acc = 0.f;
#pragma unroll
    for (int s = 0; s < TOPK; ++s) {
        int e = top_idx[token * TOPK + s];
        float w = top_w[token * TOPK + s];
        int p = pair_of[token * TOPK + s];
        acc += w * (y[(size_t)p * DIM + j] + b2[(size_t)e * DIM + j]);
    }
    out[(size_t)token * DIM + j] = acc;
}

extern "C" void kernel_launch(void* const* d_in, const int* in_sizes, int n_in,
                              void* d_out, int out_size, void* d_ws, size_t ws_size,
                              hipStream_t stream) {
    const float* x        = (const float*)d_in[0];
    const float* gate_w   = (const float*)d_in[1];
    const float* gate_b   = (const float*)d_in[2];
    const float* w1       = (const float*)d_in[3];
    const float* b1       = (const float*)d_in[4];
    const float* w2       = (const float*)d_in[5];
    const float* b2       = (const float*)d_in[6];
    const float* load_ema = (const float*)d_in[7];
    float* out = (float*)d_out;

    char* base = (char*)d_ws;
    size_t off = 0;
    auto alloc = [&](size_t bytes) {
        void* p = base + off;
        off = (off + bytes + 255) & ~(size_t)255;
        return p;
    };
    float* probs_mat = (float*)alloc(N_TOK * 32 * sizeof(float));
    int*   top_idx   = (int*)  alloc(N_TOK * TOPK * sizeof(int));
    float* top_w     = (float*)alloc(N_TOK * TOPK * sizeof(float));
    int*   counts    = (int*)  alloc(32 * sizeof(int));
    int*   offsets   = (int*)  alloc(33 * sizeof(int));
    int*   cursors   = (int*)  alloc(32 * sizeof(int));
    int*   pair_token= (int*)  alloc(N_TOK * TOPK * sizeof(int));
    int*   pair_of   = (int*)  alloc(N_TOK * TOPK * sizeof(int));
    __hip_bfloat16* xb = (__hip_bfloat16*)alloc((size_t)N_TOK * DIM * sizeof(__hip_bfloat16));
    __hip_bfloat16* h  = (__hip_bfloat16*)alloc((size_t)N_TOK * TOPK * FFN * sizeof(__hip_bfloat16));
    float* y         = (float*)alloc((size_t)N_TOK * TOPK * DIM * sizeof(float));

    router_kernel<<<N_TOK, 256, 0, stream>>>(x, gate_w, gate_b, probs_mat, top_idx, top_w);
    aux_kernel<<<1, 256, 0, stream>>>(probs_mat, top_idx, load_ema, counts, offsets, cursors,
                                      out + (size_t)N_TOK * DIM);
    scatter_kernel<<<(N_TOK + 255) / 256, 256, 0, stream>>>(top_idx, cursors, pair_token, pair_of);
    convert_x_kernel<<<(N_TOK * DIM / 4 + 255) / 256, 256, 0, stream>>>(x, xb);
    {
        dim3 grid(FFN / TN, (N_TOK * 1 + TM - 1) / TM, NE);  // y covers worst-case Me=1024
        gemm1_kernel<<<grid, 256, 0, stream>>>(xb, w1, b1, offsets, pair_token, h);
    }
    {
        dim3 grid(DIM / TN, (N_TOK * 1 + TM - 1) / TM, NE);
        gemm2_kernel<<<grid, 256, 0, stream>>>(h, w2, offsets, y);
    }
    {
        dim3 grid(DIM / 256, N_TOK);
        combine_kernel<<<grid, 256, 0, stream>>>(y, b2, top_idx, top_w, pair_of, out);
    }
}

// Round 3
// 664.116 us; speedup vs baseline: 1.6968x; 1.1434x over previous
//
#include <hip/hip_runtime.h>
#include <hip/hip_bf16.h>
#include <cmath>

#define N_TOK 1024
#define DIM   1024
#define FFN   2048
#define NE    32
#define TOPK  4
#define TM    192
#define TN    64
#define BK    32
#define BS_STRIDE 40   // bf16 elems per Bs row (80 B): 2-way bank aliasing only

typedef __attribute__((ext_vector_type(8))) short bf16x8;
typedef __attribute__((ext_vector_type(4))) float f32x4;

#define GLOBAL_AS __attribute__((address_space(1)))
#define LDS_AS    __attribute__((address_space(3)))

__device__ __forceinline__ void g2lds16(const void* g, void* l) {
    __builtin_amdgcn_global_load_lds((const GLOBAL_AS void*)g, (LDS_AS void*)l, 16, 0, 0);
}

// ---------------- router (+ x->bf16): logits, probs, top-4 ----------------
__global__ __launch_bounds__(256) void router_kernel(
        const float* __restrict__ x, const float* __restrict__ gw,
        const float* __restrict__ gb, float* __restrict__ probs_mat,
        int* __restrict__ top_idx, float* __restrict__ top_w,
        __hip_bfloat16* __restrict__ xb) {
    __shared__ float part[8][32];
    __shared__ float logit_s[32];
    int t = threadIdx.x;
    int token = blockIdx.x;
    const float* xr = x + (size_t)token * DIM;
    // fused convert x -> bf16
    {
        float4 v = *(const float4*)&xr[t * 4];
        union { __hip_bfloat16 h[4]; ushort4 u; } pk;
        pk.h[0] = __float2bfloat16(v.x); pk.h[1] = __float2bfloat16(v.y);
        pk.h[2] = __float2bfloat16(v.z); pk.h[3] = __float2bfloat16(v.w);
        *(ushort4*)&xb[(size_t)token * DIM + t * 4] = pk.u;
    }
    int e = t & 31, p = t >> 5;
    float acc = 0.f;
    int i0 = p * (DIM / 8);
    for (int i = 0; i < DIM / 8; ++i)
        acc += xr[i0 + i] * gw[(size_t)(i0 + i) * NE + e];
    part[p][e] = acc;
    __syncthreads();
    if (t < 64) {
        float l = -3e38f;
        if (t < 32) {
            l = gb[t];
            for (int q = 0; q < 8; ++q) l += part[q][t];
        }
        // full-softmax probs (for aux)
        float m = l;
        for (int off = 32; off >= 1; off >>= 1) m = fmaxf(m, __shfl_xor(m, off, 64));
        float ex = (t < 32) ? expf(l - m) : 0.f;
        float den = ex;
        for (int off = 32; off >= 1; off >>= 1) den += __shfl_xor(den, off, 64);
        if (t < 32) probs_mat[(size_t)token * 32 + t] = ex / den;
        // top-4 via wave max + ballot (lowest index on ties, like lax.top_k)
        float v = l;
        float vals[TOPK]; int idxs[TOPK];
        for (int r = 0; r < TOPK; ++r) {
            float mv = v;
            for (int off = 32; off >= 1; off >>= 1) mv = fmaxf(mv, __shfl_xor(mv, off, 64));
            unsigned long long mask = __ballot(v == mv);
            int idx = __ffsll((unsigned long long)(mask & 0xffffffffull)) - 1;
            vals[r] = mv; idxs[r] = idx;
            if (t == idx) v = -3e38f;
        }
        if (t == 0) {
            float w[TOPK]; float ss = 0.f;
            for (int r = 0; r < TOPK; ++r) { w[r] = expf(vals[r] - vals[0]); ss += w[r]; }
            for (int r = 0; r < TOPK; ++r) {
                top_idx[token * TOPK + r] = idxs[r];
                top_w[token * TOPK + r] = w[r] / ss;
            }
        }
    }
}

// ---------------- aux loss + counts + offsets (1 block) ----------------
__global__ void aux_kernel(const float* __restrict__ probs_mat, const int* __restrict__ top_idx,
                           const float* __restrict__ load_ema, int* __restrict__ offsets,
                           int* __restrict__ cursors, float* __restrict__ out_aux) {
    __shared__ int cnt_s[32];
    __shared__ float ps[32];
    __shared__ float psum_part[8][32];
    int t = threadIdx.x;
    if (t < 32) cnt_s[t] = 0;
    __syncthreads();
    for (int i = t; i < N_TOK * TOPK; i += 256) atomicAdd(&cnt_s[top_idx[i]], 1);
    int e = t & 31, p = t >> 5;
    float s = 0.f;
    for (int tok = p; tok < N_TOK; tok += 8) s += probs_mat[(size_t)tok * 32 + e];
    psum_part[p][e] = s;
    __syncthreads();
    if (t < 32) {
        float tot = 0.f;
        for (int q = 0; q < 8; ++q) tot += psum_part[q][t];
        ps[t] = tot;
    }
    __syncthreads();
    if (t == 0) {
        int off = 0;
        for (int i = 0; i < 32; ++i) { offsets[i] = off; cursors[i] = off; off += cnt_s[i]; }
        offsets[32] = off;
        float base = 0.f;
        for (int i = 0; i < 32; ++i) {
            float frac = (float)cnt_s[i] / (float)(N_TOK * TOPK);
            base += frac * (ps[i] / (float)N_TOK);
        }
        base *= (float)NE;
        float sum_ema = 0.f;
        for (int i = 0; i < 32; ++i) sum_ema += load_ema[i];
        float H = 0.f;
        for (int i = 0; i < 32; ++i) {
            float lp = load_ema[i] / (sum_ema + 1e-8f);
            H -= lp * logf(lp + 1e-8f);
        }
        *out_aux = base + 0.001f * (logf((float)NE) - H);
    }
}

// ---------------- scatter token-expert pairs ----------------
__global__ void scatter_kernel(const int* __restrict__ top_idx, int* __restrict__ cursors,
                               int* __restrict__ pair_token, int* __restrict__ pair_of) {
    int token = blockIdx.x * 256 + threadIdx.x;
    if (token >= N_TOK) return;
    for (int s = 0; s < TOPK; ++s) {
        int e = top_idx[token * TOPK + s];
        int pos = atomicAdd(&cursors[e], 1);
        pair_token[pos] = token;
        pair_of[token * TOPK + s] = pos;
    }
}

// ---------------- GEMM1: h = bf16(GELU(gather(xb) @ bf16(W1[e]) + b1[e])) ----------------
// As layout: [q][m][8 bf16] (16B units) -> conflict-free ds_read_b128 + g2lds-compatible.
__global__ __launch_bounds__(256, 4) void gemm1_kernel(
        const __hip_bfloat16* __restrict__ xb, const float* __restrict__ w1,
        const float* __restrict__ b1, const int* __restrict__ offsets,
        const int* __restrict__ pair_token, __hip_bfloat16* __restrict__ h) {
    int e = blockIdx.z;
    int m0 = offsets[e], Me = offsets[e + 1] - m0;
    int f0 = blockIdx.x * TN;

    __shared__ short As[4 * TM * 8];          // 12 KB
    __shared__ __hip_bfloat16 Bs[TN * BS_STRIDE]; // 5 KB
    __shared__ int toks[TM];

    int t = threadIdx.x;
    int w = t >> 6, ln = t & 63;
    int q = ln >> 4, lj = ln & 15;
    int bn = ln, bkb = w * 8;

    float bias[4];
#pragma unroll
    for (int ns = 0; ns < 4; ++ns) bias[ns] = b1[(size_t)e * FFN + f0 + ns * 16 + lj];

    for (int mb = 0; mb < Me; mb += TM) {
        int mlim = Me - mb; if (mlim > TM) mlim = TM;
        if (t < TM) {
            int r = t < mlim ? t : mlim - 1;
            toks[t] = pair_token[m0 + mb + r];
        }
        f32x4 acc[3][4] = {};
        for (int k0 = 0; k0 < DIM; k0 += BK) {
            __syncthreads();
            // A: gathered token rows, q-block = this wave's k-subblock
#pragma unroll
            for (int c = 0; c < 3; ++c) {
                const __hip_bfloat16* src = xb + (size_t)toks[c * 64 + ln] * DIM + k0 + w * 8;
                g2lds16(src, As + (w * TM + c * 64) * 8);
            }
            // B: fp32 -> bf16, [n][k] stride 40
            {
                const float* bp = w1 + ((size_t)e * DIM + k0 + bkb) * FFN + f0 + bn;
                union { __hip_bfloat16 hb[8]; int4 v; } u;
#pragma unroll
                for (int j = 0; j < 8; ++j) u.hb[j] = __float2bfloat16(bp[(size_t)j * FFN]);
                *(int4*)&Bs[bn * BS_STRIDE + bkb] = u.v;
            }
            __syncthreads();
            bf16x8 af[3], bf[4];
#pragma unroll
            for (int ms = 0; ms < 3; ++ms)
                af[ms] = *(const bf16x8*)&As[(q * TM + w * 48 + ms * 16 + lj) * 8];
#pragma unroll
            for (int ns = 0; ns < 4; ++ns)
                bf[ns] = *(const bf16x8*)&Bs[(ns * 16 + lj) * BS_STRIDE + q * 8];
#pragma unroll
            for (int ms = 0; ms < 3; ++ms)
#pragma unroll
                for (int ns = 0; ns < 4; ++ns)
                    acc[ms][ns] = __builtin_amdgcn_mfma_f32_16x16x32_bf16(af[ms], bf[ns], acc[ms][ns], 0, 0, 0);
        }
#pragma unroll
        for (int ms = 0; ms < 3; ++ms) {
#pragma unroll
            for (int rr = 0; rr < 4; ++rr) {
                int rit = w * 48 + ms * 16 + q * 4 + rr;
                if (rit >= mlim) continue;
                size_t rowG = (size_t)(m0 + mb + rit);
#pragma unroll
                for (int ns = 0; ns < 4; ++ns) {
                    float v = acc[ms][ns][rr] + bias[ns];
                    float g = 0.5f * v * (1.f + erff(v * 0.70710678118654752f));
                    h[rowG * FFN + f0 + ns * 16 + lj] = __float2bfloat16(g);
                }
            }
        }
    }
}

// ---------------- GEMM2 (split-K x2): ypart = h[:, kh] @ bf16(W2[e][kh, :]) ----------------
__global__ __launch_bounds__(256, 4) void gemm2_kernel(
        const __hip_bfloat16* __restrict__ h, const float* __restrict__ w2,
        const int* __restrict__ offsets, float* __restrict__ y) {
    int e = blockIdx.z;
    int m0 = offsets[e], Me = offsets[e + 1] - m0;
    int d0 = blockIdx.x * TN;
    int kbase = blockIdx.y * (FFN / 2);
    float* yp = y + (size_t)blockIdx.y * N_TOK * TOPK * DIM;

    __shared__ short As[4 * TM * 8];
    __shared__ __hip_bfloat16 Bs[TN * BS_STRIDE];

    int t = threadIdx.x;
    int w = t >> 6, ln = t & 63;
    int q = ln >> 4, lj = ln & 15;
    int bn = ln, bkb = w * 8;

    for (int mb = 0; mb < Me; mb += TM) {
        int mlim = Me - mb; if (mlim > TM) mlim = TM;
        f32x4 acc[3][4] = {};
        for (int k0 = 0; k0 < FFN / 2; k0 += BK) {
            __syncthreads();
#pragma unroll
            for (int c = 0; c < 3; ++c) {
                int rit = c * 64 + ln;
                int r = rit < mlim ? rit : mlim - 1;
                const __hip_bfloat16* src = h + (size_t)(m0 + mb + r) * FFN + kbase + k0 + w * 8;
                g2lds16(src, As + (w * TM + c * 64) * 8);
            }
            {
                const float* bp = w2 + ((size_t)e * FFN + kbase + k0 + bkb) * DIM + d0 + bn;
                union { __hip_bfloat16 hb[8]; int4 v; } u;
#pragma unroll
                for (int j = 0; j < 8; ++j) u.hb[j] = __float2bfloat16(bp[(size_t)j * DIM]);
                *(int4*)&Bs[bn * BS_STRIDE + bkb] = u.v;
            }
            __syncthreads();
            bf16x8 af[3], bf[4];
#pragma unroll
            for (int ms = 0; ms < 3; ++ms)
                af[ms] = *(const bf16x8*)&As[(q * TM + w * 48 + ms * 16 + lj) * 8];
#pragma unroll
            for (int ns = 0; ns < 4; ++ns)
                bf[ns] = *(const bf16x8*)&Bs[(ns * 16 + lj) * BS_STRIDE + q * 8];
#pragma unroll
            for (int ms = 0; ms < 3; ++ms)
#pragma unroll
                for (int ns = 0; ns < 4; ++ns)
                    acc[ms][ns] = __builtin_amdgcn_mfma_f32_16x16x32_bf16(af[ms], bf[ns], acc[ms][ns], 0, 0, 0);
        }
#pragma unroll
        for (int ms = 0; ms < 3; ++ms) {
#pragma unroll
            for (int rr = 0; rr < 4; ++rr) {
                int rit = w * 48 + ms * 16 + q * 4 + rr;
                if (rit >= mlim) continue;
                size_t rowG = (size_t)(m0 + mb + rit);
#pragma unroll
                for (int ns = 0; ns < 4; ++ns)
                    yp[rowG * DIM + d0 + ns * 16 + lj] = acc[ms][ns][rr];
            }
        }
    }
}

// ---------------- combine: out = sum_s w_s * (y0 + y1 + b2[e_s]) ----------------
__global__ void combine_kernel(const float* __restrict__ y, const float* __restrict__ b2,
        const int* __restrict__ top_idx, const float* __restrict__ top_w,
        const int* __restrict__ pair_of, float* __restrict__ out) {
    const float* y1 = y + (size_t)N_TOK * TOPK * DIM;
    int token = blockIdx.y;
    int j = blockIdx.x * 256 + threadIdx.x;
    float acc = 0.f;
#pragma unroll
    for (int s = 0; s < TOPK; ++s) {
        int e = top_idx[token * TOPK + s];
        float w = top_w[token * TOPK + s];
        int p = pair_of[token * TOPK + s];
        acc += w * (y[(size_t)p * DIM + j] + y1[(size_t)p * DIM + j] + b2[(size_t)e * DIM + j]);
    }
    out[(size_t)token * DIM + j] = acc;
}

extern "C" void kernel_launch(void* const* d_in, const int* in_sizes, int n_in,
                              void* d_out, int out_size, void* d_ws, size_t ws_size,
                              hipStream_t stream) {
    const float* x        = (const float*)d_in[0];
    const float* gate_w   = (const float*)d_in[1];
    const float* gate_b   = (const float*)d_in[2];
    const float* w1       = (const float*)d_in[3];
    const float* b1       = (const float*)d_in[4];
    const float* w2       = (const float*)d_in[5];
    const float* b2       = (const float*)d_in[6];
    const float* load_ema = (const float*)d_in[7];
    float* out = (float*)d_out;

    char* base = (char*)d_ws;
    size_t off = 0;
    auto alloc = [&](size_t bytes) {
        void* p = base + off;
        off = (off + bytes + 255) & ~(size_t)255;
        return p;
    };
    float* probs_mat = (float*)alloc(N_TOK * 32 * sizeof(float));
    int*   top_idx   = (int*)  alloc(N_TOK * TOPK * sizeof(int));
    float* top_w     = (float*)alloc(N_TOK * TOPK * sizeof(float));
    int*   offsets   = (int*)  alloc(33 * sizeof(int));
    int*   cursors   = (int*)  alloc(32 * sizeof(int));
    int*   pair_token= (int*)  alloc(N_TOK * TOPK * sizeof(int));
    int*   pair_of   = (int*)  alloc(N_TOK * TOPK * sizeof(int));
    __hip_bfloat16* xb = (__hip_bfloat16*)alloc((size_t)N_TOK * DIM * sizeof(__hip_bfloat16));
    __hip_bfloat16* h  = (__hip_bfloat16*)alloc((size_t)N_TOK * TOPK * FFN * sizeof(__hip_bfloat16));
    float* y         = (float*)alloc((size_t)2 * N_TOK * TOPK * DIM * sizeof(float));

    router_kernel<<<N_TOK, 256, 0, stream>>>(x, gate_w, gate_b, probs_mat, top_idx, top_w, xb);
    aux_kernel<<<1, 256, 0, stream>>>(probs_mat, top_idx, load_ema, offsets, cursors,
                                      out + (size_t)N_TOK * DIM);
    scatter_kernel<<<(N_TOK + 255) / 256, 256, 0, stream>>>(top_idx, cursors, pair_token, pair_of);
    {
        dim3 grid(FFN / TN, 1, NE);
        gemm1_kernel<<<grid, 256, 0, stream>>>(xb, w1, b1, offsets, pair_token, h);
    }
    {
        dim3 grid(DIM / TN, 2, NE);
        gemm2_kernel<<<grid, 256, 0, stream>>>(h, w2, offsets, y);
    }
    {
        dim3 grid(DIM / 256, N_TOK);
        combine_kernel<<<grid, 256, 0, stream>>>(y, b2, top_idx, top_w, pair_of, out);
    }
}